// Round 12
// baseline (331.870 us; speedup 1.0000x reference)
//
#include <hip/hip_runtime.h>
#include <hip/hip_bf16.h>

// Fused Conv3d(3->16,k=3,valid) + conv_b + ReLU + maxpool2x2x2
// + spatial mean(fp32) + /2 + bias + channel-sum  ->  out[32] fp32.
//
// R21: single-dispatch — init_kernel deleted (the last removable serial work).
//  - af[9] weight frags computed per-lane from conv_w in the prologue
//    (72 clamped loads, L2-hot, ~400cy once per 15-iter block).
//  - out zeroed via hipMemsetAsync(d_out, 0, out_size, stream) (capture-legal);
//    the hp==0 block adds the full bias_sum once inside its final atomicAdd
//    (no fp distribution error; add order was already nondeterministic).
//  - d_ws unused.
// Ledger (R13-R20): conv ~93us = serialized pipe sum (LDS ~47 + VALU ~32 +
//  MFMA ~29); all overlap levers null: latency depth (R11), LDS-read cut
//  (R13), barrier halving (R14), 4x256-thr blocks (R16), barrier-free
//  1-wave (R17-19). Only raw work-cuts paid (R10 -28us, R12 -18us).
//
// R12 design (verified absmax=0 x3): operand-swapped MFMA
//  (M=(wi,hh) spatial, N=(ch,dd), col=2ch+dd) -> acc[4a..4a+3] = one 2x2
//  h/w pool window pooled IN-REGISTER; dd-pool = DPP ^1; +conv_b+relu
//  post-pool (monotone). D-plane rotation: stage only pair dp+2 per iter
//  (parity ^16 addr, buffer = ((dp+hs)>>1)&1). ci-fast k-slots, XOR bank
//  swizzle, lgkm-only BAR (globals in flight), XCD bijective swizzle.
//  MFMA m32n32k16, D: col=lane&31, row=(reg&3)+8*(reg>>2)+4*(lane>>5).

typedef __attribute__((ext_vector_type(8)))  short  short8;
typedef __attribute__((ext_vector_type(2)))  float  floatx2;
typedef __attribute__((ext_vector_type(4)))  float  floatx4;
typedef __attribute__((ext_vector_type(16))) float  floatx16;

__device__ __forceinline__ short f2bf(float f) {
    unsigned u = __builtin_bit_cast(unsigned, f);
    unsigned r = (u + 0x7FFFu + ((u >> 16) & 1u)) >> 16;
    return (short)r;
}

__device__ __forceinline__ unsigned pkbf2(float a, float b) {
    __hip_bfloat162 h = __float22bfloat162_rn(float2{a, b});  // v_cvt_pk_bf16_f32
    unsigned r;
    __builtin_memcpy(&r, &h, 4);
    return r;
}

template <int CTRL>
__device__ __forceinline__ float dpp_max(float v) {
    int x = __builtin_bit_cast(int, v);
    int y = __builtin_amdgcn_mov_dpp(x, CTRL, 0xF, 0xF, true);
    return fmaxf(v, __builtin_bit_cast(float, y));
}

// LDS-only barrier: drain DS ops, leave global loads in flight (no vmcnt).
#define BAR() asm volatile("s_waitcnt lgkmcnt(0)\n\ts_barrier" ::: "memory")

#define BUFSZ 16640

__global__ __launch_bounds__(512, 4) void fused_conv_pool_reduce(
    const float* __restrict__ xg,    // f32 [32][3][32][128][128]
    const float* __restrict__ wg,    // f32 [16][3][3][3][3]
    const float* __restrict__ cbg,   // f32 [16] conv bias
    const float* __restrict__ biasg, // f32 [16] post bias
    float* __restrict__ out)         // f32 [32], pre-zeroed via memset
{
    __shared__ __align__(16) short rawT[2 * 130 * 64];  // 33,280 B (2 buffers)
    __shared__ float wsums[8];

    // XCD-aware bijective swizzle: 2016 = 8 XCDs x 252 (4 b x 63 hp each).
    const int lin = blockIdx.y * 63 + blockIdx.x;      // 0..2015
    const int nl  = (lin & 7) * 252 + (lin >> 3);
    const int hp  = nl % 63;
    const int b   = nl / 63;

    const int tid = threadIdx.x;  // 0..511
    const int lane = tid & 63;
    const int wv   = tid >> 6;    // wave = 16-wide w tile
    const int hs   = lane >> 5;

    // ---- B-frags computed in-kernel from conv_w (init_kernel deleted) ----
    // col n = lane&31 = 2*ch + dd; k-slot rel s = hs*8 + j: dl_rel = s>>2,
    // ci = s&3 (ci-fast); kd = dl_rel - dd; zero-pad OOB taps.
    short8 af[9];
    {
        const int m = lane & 31;
        const int ch = m >> 1, dd = m & 1;
        const float* wch = wg + ch * 81;
        #pragma unroll
        for (int f = 0; f < 9; ++f) {
            const int kh = f / 3, kw = f % 3;     // compile-time per f
            short8 v;
            #pragma unroll
            for (int j = 0; j < 8; ++j) {
                const int s = hs * 8 + j;
                const int dl = s >> 2, ci = s & 3;
                const int kd = dl - dd;
                const bool ok = (ci < 3) && (kd >= 0) && (kd < 3);
                const int idx = ok ? (ci * 27 + kd * 9 + kh * 3 + kw) : 0;
                const float wvle = wch[idx];      // always in-bounds
                v[j] = ok ? f2bf(wvle) : (short)0;
            }
            af[f] = v;
        }
    }
    const float cbv = cbg[(lane >> 1) & 15];   // ch = (lane&31)>>1
    float maskA[4];
    #pragma unroll
    for (int a = 0; a < 4; ++a) {
        const bool ok = ((lane & 1) == 0) && (wv * 8 + 2 * a + hs <= 62);
        maskA[a] = ok ? 1.0f : 0.0f;
    }

    // ---- zero rows 128/129 of both buffers (once) ----
    if (tid < 64)
        *(unsigned long long*)((char*)rawT + (tid >> 5) * BUFSZ + 16384 + (tid & 31) * 8) = 0ULL;

    #define SWZ(r) (((r) ^ ((r) >> 3)) & 7)

    // ---- per-iter stage map: 2 planes (pair dp+2), 2 rows x 8B per thread ----
    const int w4 = tid & 31, dr2 = (tid >> 5) & 1, rr = (tid >> 6) & 1, hr2 = (tid >> 7) & 3;
    int waddr2[2];
    #pragma unroll
    for (int j = 0; j < 2; ++j) {
        const int row = 2 * w4 + 64 * rr + j;
        waddr2[j] = row * 128 + ((hr2 * 2) ^ SWZ(row)) * 16 + dr2 * 8;  // ^ (p<<4) at runtime
    }

    // ---- read map (A = spatial): row = wv*16 + wi + kw, chunk = (hh+kh)*2 + hs ----
    const int wi = (lane >> 1) & 15, hh = lane & 1;
    int raddr[3][3];
    #pragma unroll
    for (int kh = 0; kh < 3; ++kh) {
        #pragma unroll
        for (int kw = 0; kw < 3; ++kw) {
            const int row = wv * 16 + wi + kw;
            const int phys = ((hh + kh) * 2 + hs) ^ SWZ(row);
            raddr[kh][kw] = row * 128 + phys * 16;   // ^ (p<<4) + rbuf*BUFSZ at runtime
        }
    }

    // ---- prologue: stage pairs 0,1 (planes 0..3) into buffer 0 ----
    {
        const int w4p = tid & 31, drp = (tid >> 5) & 3, hrp = (tid >> 7) & 3;
        const float* srcP = xg + ((size_t)b * 96 + drp) * 16384 + (2 * hp + hrp) * 128 + 4 * w4p;
        const floatx4 c0 = *(const floatx4*)(srcP);
        const floatx4 c1 = *(const floatx4*)(srcP + 524288);
        const floatx4 c2 = *(const floatx4*)(srcP + 1048576);
        const int chunkL = hrp * 2 + (drp >> 1);
        #pragma unroll
        for (int i = 0; i < 4; ++i) {
            const int row = 4 * w4p + i;
            const int ad = row * 128 + (chunkL ^ SWZ(row)) * 16 + (drp & 1) * 8;
            uint2 pk;
            pk.x = pkbf2(c0[i], c1[i]);
            pk.y = pkbf2(c2[i], 0.0f);
            *(uint2*)((char*)rawT + ad) = pk;
        }
    }

    // ---- prologue prefetch: pair 2 (planes 4,5), float2 per ci ----
    const float* src2 = xg + ((size_t)b * 96 + 4 + dr2) * 16384
                      + (2 * hp + hr2) * 128 + 2 * w4 + 64 * rr;
    floatx2 A0 = *(const floatx2*)(src2);
    floatx2 A1 = *(const floatx2*)(src2 + 524288);
    floatx2 A2 = *(const floatx2*)(src2 + 1048576);

    float vsum = 0.f;
    for (int dp = 0; dp < 15; ++dp) {
        const int p16 = (dp & 1) << 4;
        if (dp <= 13) {
            // stage pair dp+2 into buffer ((dp>>1)+1)&1, chunk-group = dp&1
            const int bw = (((dp >> 1) + 1) & 1) * BUFSZ;
            uint2 pk0, pk1;
            pk0.x = pkbf2(A0[0], A1[0]); pk0.y = pkbf2(A2[0], 0.0f);
            pk1.x = pkbf2(A0[1], A1[1]); pk1.y = pkbf2(A2[1], 0.0f);
            *(uint2*)((char*)rawT + bw + (waddr2[0] ^ p16)) = pk0;
            *(uint2*)((char*)rawT + bw + (waddr2[1] ^ p16)) = pk1;
            if (dp <= 12) {     // prefetch pair dp+3 (full-iter latency cover)
                src2 += 32768;
                A0 = *(const floatx2*)(src2);
                A1 = *(const floatx2*)(src2 + 524288);
                A2 = *(const floatx2*)(src2 + 1048576);
            }
        }
        BAR();   // LDS-only; global loads stay in flight

        // read buffer per lane-half: pair (dp+hs) -> buffer ((dp+hs)>>1)&1
        const int roff = (((dp + hs) >> 1) & 1) * BUFSZ;

        floatx16 acc = {0.f,0.f,0.f,0.f,0.f,0.f,0.f,0.f,
                        0.f,0.f,0.f,0.f,0.f,0.f,0.f,0.f};
        #pragma unroll
        for (int kh = 0; kh < 3; ++kh) {
            #pragma unroll
            for (int kw = 0; kw < 3; ++kw) {
                const short8 bf = *(const short8*)((char*)rawT + roff + (raddr[kh][kw] ^ p16));
                acc = __builtin_amdgcn_mfma_f32_32x32x16_bf16(bf, af[kh * 3 + kw], acc, 0, 0, 0);
            }
        }
        // epilogue: acc[4a..4a+3] = one 2x2 h/w window (in-reg max),
        // dd-pool = DPP ^1, then +cb, relu, masked accumulate.
        #pragma unroll
        for (int a = 0; a < 4; ++a) {
            float m01 = fmaxf(acc[4 * a],     acc[4 * a + 1]);
            float m23 = fmaxf(acc[4 * a + 2], acc[4 * a + 3]);
            float m   = fmaxf(m01, m23);
            m = dpp_max<0xB1>(m);                 // pool over dd (lane ^ 1)
            const float v = fmaxf(m + cbv, 0.f);  // +conv_b, relu (post-pool)
            vsum = fmaf(maskA[a], v, vsum);
        }
    }

    // mask already zeroes invalid lanes/groups: plain full-wave sum
    float s = vsum;
    #pragma unroll
    for (int off = 1; off < 64; off <<= 1) s += __shfl_xor(s, off, 64);

    if (lane == 0) wsums[wv] = s;
    __syncthreads();
    if (tid == 0) {
        float bs = 0.f;
        #pragma unroll
        for (int i = 0; i < 8; ++i) bs += wsums[i];
        float add = bs * (1.0f / 119070.0f);   // /(15*63*63)/2
        if (hp == 0) {                          // bias_sum added exactly once per b
            float bsum = 0.f;
            #pragma unroll
            for (int cc = 0; cc < 16; ++cc) bsum += biasg[cc];
            add += bsum;
        }
        atomicAdd(&out[b], add);
    }
}

extern "C" void kernel_launch(void* const* d_in, const int* in_sizes, int n_in,
                              void* d_out, int out_size, void* d_ws, size_t ws_size,
                              hipStream_t stream) {
    const float* x      = (const float*)d_in[0];
    const float* conv_w = (const float*)d_in[1];
    const float* conv_b = (const float*)d_in[2];
    const float* bias   = (const float*)d_in[3];
    float* out = (float*)d_out;

    hipMemsetAsync(out, 0, out_size, stream);   // 128 B, capture-legal
    dim3 grid(63, 32);  // (hp, b) pre-swizzle
    fused_conv_pool_reduce<<<grid, 512, 0, stream>>>(x, conv_w, conv_b, bias, out);
}